// Round 1
// 260.947 us; speedup vs baseline: 1.0563x; 1.0563x over previous
//
#include <hip/hip_runtime.h>
#include <hip/hip_bf16.h>

typedef __attribute__((ext_vector_type(8))) _Float16 hfrag;
typedef __attribute__((ext_vector_type(4))) float ffrag;

// bucket = 256 consecutive nodes; supports N <= 131072 (static LDS hist arrays)
#define BSH 8
#define LBS 256

__device__ __forceinline__ float b2f_(unsigned short u) {
    return __uint_as_float(((unsigned)u) << 16);
}
__device__ __forceinline__ unsigned short f2b_(float v) {
    __hip_bfloat16 h = __float2bfloat16(v);   // RNE
    return *reinterpret_cast<unsigned short*>(&h);
}
__device__ __forceinline__ unsigned short f2h_(float v) {
    _Float16 h = (_Float16)v;                 // RNE
    return __builtin_bit_cast(unsigned short, h);
}
__device__ __forceinline__ float h2f_(unsigned short u) {
    _Float16 h = __builtin_bit_cast(_Float16, u);
    return (float)h;
}

__device__ __forceinline__ float loadF(const void* p, long long i, int isF32) {
    if (isF32) return ((const float*)p)[i];
    return b2f_(((const unsigned short*)p)[i]);
}

__device__ __forceinline__ float4 loadF4(const void* p, long long base, int i4, int isF32) {
    if (isF32) {
        return ((const float4*)((const float*)p + base))[i4];
    } else {
        ushort4 u = ((const ushort4*)((const unsigned short*)p + base))[i4];
        return make_float4(b2f_(u.x), b2f_(u.y), b2f_(u.z), b2f_(u.w));
    }
}

__device__ __forceinline__ float4 loadH4(const unsigned short* p, long long base, int i4) {
    ushort4 u = ((const ushort4*)(p + base))[i4];
    return make_float4(h2f_(u.x), h2f_(u.y), h2f_(u.z), h2f_(u.w));
}

__device__ __forceinline__ void get_edge(const int* ei, int i64, int e, int E, int& s, int& d) {
    if (i64) { s = ei[2 * (long long)e]; d = ei[2 * (long long)E + 2 * (long long)e]; }
    else     { s = ei[e];                d = ei[(long long)E + e]; }
}

__device__ __forceinline__ int2 fetchE(const int2* pke, int p, int end) {
    int pc = max(min(p, end - 1), 0);
    int2 v = pke[pc];
    v.y = (p < end) ? v.y : 0;
    return v;
}

// ---- fused: dtype detect (per-block, deterministic) + weight conv (block 0)
//      + x -> fp16 conversion + coarse bucket counts ----
__global__ __launch_bounds__(256) void k_cc(const void* __restrict__ x,
                                            const int* __restrict__ ei,
                                            const void* __restrict__ W1, const void* __restrict__ b1,
                                            const void* __restrict__ W2, const void* __restrict__ b2,
                                            int E, int N, int nbk,
                                            int* __restrict__ flags, float* __restrict__ Wbuf,
                                            int* __restrict__ dcnt_g, int* __restrict__ scnt_g,
                                            unsigned short* __restrict__ xh) {
    __shared__ int h[1024];   // [0..512): dst-bucket, [512..1024): src-bucket
    __shared__ int s_sane, s_zero;
    int tid = threadIdx.x;
    if (tid == 0) { s_sane = 0; s_zero = 0; }
    for (int i = tid; i < 1024; i += 256) h[i] = 0;
    __syncthreads();
    // dtype detection — every block reads the same data -> identical result
    const unsigned short* xu = (const unsigned short*)x;
    int sane = 0;
    for (int k = tid; k < 4096; k += 256) {
        float v = b2f_(xu[2 * k]);
        float a = fabsf(v);
        if (v == 0.0f || (a >= 9.3e-10f && a <= 1.1e9f)) sane++;
    }
    if (sane) atomicAdd(&s_sane, sane);
    int zero = 0;
    for (int k = tid; k < 1024; k += 256) if (ei[2 * k + 1] == 0) zero++;
    if (zero) atomicAdd(&s_zero, zero);
    __syncthreads();
    int f   = (s_sane < 3000) ? 1 : 0;   // 1 = f32 input
    int i64 = (s_zero > 512) ? 1 : 0;
    if (blockIdx.x == 0) {
        if (tid == 0) { flags[0] = f; flags[1] = i64; }
        for (int i = tid; i < 4096; i += 256) Wbuf[i] = loadF(W1, i, f);
        if (tid < 64) Wbuf[4096 + tid] = loadF(b1, tid, f);
        for (int i = tid; i < 1024; i += 256) Wbuf[4160 + i] = loadF(W2, i, f);
        if (tid < 16) Wbuf[5184 + tid] = loadF(b2, tid, f);
    }
    int gstride = blockDim.x * gridDim.x;
    // x -> fp16 (halves the gather footprint of k_agg)
    int n4 = N * 16;   // float4-groups
    for (int i = blockIdx.x * blockDim.x + tid; i < n4; i += gstride) {
        float4 v = loadF4(x, 0, i, f);
        ushort4 o;
        o.x = f2h_(v.x); o.y = f2h_(v.y); o.z = f2h_(v.z); o.w = f2h_(v.w);
        ((ushort4*)xh)[i] = o;
    }
    // coarse bucket counts
    for (int e = blockIdx.x * blockDim.x + tid; e < E; e += gstride) {
        int s, d;
        get_edge(ei, i64, e, E, s, d);
        atomicAdd(&h[d >> BSH], 1);
        atomicAdd(&h[512 + (s >> BSH)], 1);
    }
    __syncthreads();
    for (int i = tid; i < nbk; i += 256) {
        if (h[i])       atomicAdd(&dcnt_g[i], h[i]);
        if (h[512 + i]) atomicAdd(&scnt_g[i], h[512 + i]);
    }
}

// ---- C2: scan both bucket-count arrays -> bases + cursors; row_start[N]=E ----
__global__ void k_scan2(const int* __restrict__ dcnt, const int* __restrict__ scnt,
                        int nbk, int E, int N,
                        int* __restrict__ dbase, int* __restrict__ dcur,
                        int* __restrict__ sbase, int* __restrict__ scur,
                        int* __restrict__ row_start) {
    __shared__ int ld[512], ls[512];
    int tid = threadIdx.x;
    for (int i = tid; i < nbk; i += 256) { ld[i] = dcnt[i]; ls[i] = scnt[i]; }
    __syncthreads();
    if (tid == 0) { int run = 0; for (int i = 0; i < nbk; ++i) { int v = ld[i]; ld[i] = run; run += v; } }
    if (tid == 1) { int run = 0; for (int i = 0; i < nbk; ++i) { int v = ls[i]; ls[i] = run; run += v; } }
    __syncthreads();
    for (int i = tid; i < nbk; i += 256) {
        dbase[i] = ld[i]; dcur[i] = ld[i];
        sbase[i] = ls[i]; scur[i] = ls[i];
    }
    if (tid == 0) { dbase[nbk] = E; sbase[nbk] = E; row_start[N] = E; }
}

// ---- C3: bucket-fill via per-block LDS count + chunk claim + plain stores ----
// dst-stream: packed (src<<8)|(dst&255) int; src-stream: (src&255) byte
__global__ __launch_bounds__(256) void k_bfill(const int* __restrict__ ei,
                                               const int* __restrict__ flags, int E, int nbk,
                                               int* __restrict__ dcur_g, int* __restrict__ scur_g,
                                               int* __restrict__ pdst,
                                               unsigned char* __restrict__ psrc) {
    __shared__ int hd[512], hs[512], bd[512], bs[512];
    int tid = threadIdx.x;
    for (int i = tid; i < 512; i += 256) { hd[i] = 0; hs[i] = 0; }
    __syncthreads();
    int i64 = flags[1];
    int stride = blockDim.x * gridDim.x;
    for (int e = blockIdx.x * blockDim.x + tid; e < E; e += stride) {
        int s, d;
        get_edge(ei, i64, e, E, s, d);
        atomicAdd(&hd[d >> BSH], 1);
        atomicAdd(&hs[s >> BSH], 1);
    }
    __syncthreads();
    for (int i = tid; i < nbk; i += 256) {
        int v = hd[i];
        bd[i] = v ? atomicAdd(&dcur_g[i], v) : 0;
        v = hs[i];
        bs[i] = v ? atomicAdd(&scur_g[i], v) : 0;
    }
    __syncthreads();
    for (int e = blockIdx.x * blockDim.x + tid; e < E; e += stride) {
        int s, d;
        get_edge(ei, i64, e, E, s, d);
        int p = atomicAdd(&bd[d >> BSH], 1);
        pdst[p] = (s << BSH) | (d & (LBS - 1));
        int q = atomicAdd(&bs[s >> BSH], 1);
        psrc[q] = (unsigned char)(s & (LBS - 1));
    }
}

// ---- C4: exact per-node src degree per bucket -> dis = rsqrt(deg+1) ----
__global__ __launch_bounds__(256) void k_deg(const unsigned char* __restrict__ psrc,
                                             const int* __restrict__ sbase,
                                             float* __restrict__ dis, int N) {
    __shared__ int h[LBS];
    int b = blockIdx.x, tid = threadIdx.x;
    if (tid < LBS) h[tid] = 0;
    __syncthreads();
    int beg = sbase[b], end = sbase[b + 1];
    for (int p = beg + tid; p < end; p += 256) atomicAdd(&h[psrc[p]], 1);
    __syncthreads();
    if (tid < LBS) {
        int node = b * LBS + tid;
        if (node < N) dis[node] = rsqrtf((float)h[tid] + 1.0f);
    }
}

// ---- C5: exact per-node CSR within bucket: row_start + pke{src, dis[src]} ----
__global__ __launch_bounds__(256) void k_csr(const int* __restrict__ pdst,
                                             const int* __restrict__ dbase,
                                             const float* __restrict__ dis,
                                             int* __restrict__ row_start,
                                             int2* __restrict__ pke, int N) {
    __shared__ int h[LBS], lb[LBS], cur[LBS];
    int b = blockIdx.x, tid = threadIdx.x;
    if (tid < LBS) h[tid] = 0;
    __syncthreads();
    int beg = dbase[b], end = dbase[b + 1];
    for (int p = beg + tid; p < end; p += 256) atomicAdd(&h[pdst[p] & (LBS - 1)], 1);
    __syncthreads();
    if (tid == 0) { int run = 0; for (int i = 0; i < LBS; ++i) { lb[i] = run; run += h[i]; } }
    __syncthreads();
    if (tid < LBS) {
        cur[tid] = lb[tid];
        int node = b * LBS + tid;
        if (node < N) row_start[node] = beg + lb[tid];
    }
    __syncthreads();
    for (int p = beg + tid; p < end; p += 256) {
        int e = pdst[p];
        int src = e >> BSH, ld = e & (LBS - 1);
        int r = atomicAdd(&cur[ld], 1);
        pke[beg + r] = make_int2(src, __float_as_int(dis[src]));
    }
}

// ---- aggregation: AGG[n] = dd^2*x[n] + sum dd*dis[s]*x[s]  -> fp16 [N,64] ----
__global__ __launch_bounds__(256) void k_agg(const unsigned short* __restrict__ xh,
                                             const float* __restrict__ dis,
                                             const int* __restrict__ row_start,
                                             const int2* __restrict__ pke,
                                             unsigned short* __restrict__ aggb, int N) {
    int tid = threadIdx.x;
    int lane = tid & 63;
    int g = lane >> 4, i4 = lane & 15;
    int n = blockIdx.x * 4 + (tid >> 6);
    if (n >= N) return;
    float dd = dis[n];
    int beg = row_start[n], end = row_start[n + 1];
    int cnt = end - beg;
    float4 a0 = make_float4(0.f, 0.f, 0.f, 0.f), a1 = make_float4(0.f, 0.f, 0.f, 0.f);
    if (g == 0) {
        float4 xv = loadH4(xh, (long long)n * 64, i4);
        float w = dd * dd;
        a0.x = w * xv.x; a0.y = w * xv.y; a0.z = w * xv.z; a0.w = w * xv.w;
    }
    int nIt = (cnt + 3) >> 2;
    int p = beg + g;
    int2 e0 = fetchE(pke, p, end);
    int2 e1 = fetchE(pke, p + 4, end);
    int t = 0;
    for (; t + 2 <= nIt; t += 2) {
        float4 r0 = loadH4(xh, (long long)e0.x * 64, i4);
        float4 r1 = loadH4(xh, (long long)e1.x * 64, i4);
        float n0v = dd * __int_as_float(e0.y);
        float n1v = dd * __int_as_float(e1.y);
        e0 = fetchE(pke, p + 8, end);
        e1 = fetchE(pke, p + 12, end);
        p += 8;
        a0.x += n0v * r0.x; a0.y += n0v * r0.y; a0.z += n0v * r0.z; a0.w += n0v * r0.w;
        a1.x += n1v * r1.x; a1.y += n1v * r1.y; a1.z += n1v * r1.z; a1.w += n1v * r1.w;
    }
    if (t < nIt) {
        float4 r0 = loadH4(xh, (long long)e0.x * 64, i4);
        float n0v = dd * __int_as_float(e0.y);
        a0.x += n0v * r0.x; a0.y += n0v * r0.y; a0.z += n0v * r0.z; a0.w += n0v * r0.w;
    }
    a0.x += a1.x; a0.y += a1.y; a0.z += a1.z; a0.w += a1.w;
    a0.x += __shfl_xor(a0.x, 16); a0.y += __shfl_xor(a0.y, 16);
    a0.z += __shfl_xor(a0.z, 16); a0.w += __shfl_xor(a0.w, 16);
    a0.x += __shfl_xor(a0.x, 32); a0.y += __shfl_xor(a0.y, 32);
    a0.z += __shfl_xor(a0.z, 32); a0.w += __shfl_xor(a0.w, 32);
    if (g == 0) {
        ushort4 o;
        o.x = f2h_(a0.x); o.y = f2h_(a0.y); o.z = f2h_(a0.z); o.w = f2h_(a0.w);
        *(ushort4*)(aggb + (size_t)n * 64 + i4 * 4) = o;
    }
}

// ---- dense chain via f16 MFMA: T2 = relu(AGG@W1 + b1) @ W2  (fp16 in/out) ----
__global__ __launch_bounds__(256) void k_dense(const unsigned short* __restrict__ aggb,
                                               const float* __restrict__ Wbuf,
                                               unsigned short* __restrict__ t2b, int N) {
    __shared__ __align__(16) unsigned short Hs[4][16 * 72];
    int tid = threadIdx.x;
    int lane = tid & 63;
    int w = tid >> 6;
    int m = lane & 15, q = lane >> 4;
    int n0 = blockIdx.x * 64 + w * 16;
    if (n0 >= N) return;

    hfrag Bw1[2][4];
#pragma unroll
    for (int kt = 0; kt < 2; ++kt)
#pragma unroll
        for (int nt = 0; nt < 4; ++nt)
#pragma unroll
            for (int j = 0; j < 8; ++j)
                Bw1[kt][nt][j] = (_Float16)Wbuf[(kt * 32 + q * 8 + j) * 64 + nt * 16 + m];
    hfrag Bw2[2];
#pragma unroll
    for (int kt = 0; kt < 2; ++kt)
#pragma unroll
        for (int j = 0; j < 8; ++j)
            Bw2[kt][j] = (_Float16)Wbuf[4160 + (kt * 32 + q * 8 + j) * 16 + m];
    float b1n[4];
#pragma unroll
    for (int nt = 0; nt < 4; ++nt) b1n[nt] = Wbuf[4096 + nt * 16 + m];

    const unsigned short* arow = aggb + (size_t)(n0 + m) * 64 + q * 8;
    hfrag A0 = *(const hfrag*)(arow);
    hfrag A1 = *(const hfrag*)(arow + 32);

    ffrag acc[4];
#pragma unroll
    for (int nt = 0; nt < 4; ++nt) {
        ffrag z = {0.f, 0.f, 0.f, 0.f};
        z = __builtin_amdgcn_mfma_f32_16x16x32_f16(A0, Bw1[0][nt], z, 0, 0, 0);
        z = __builtin_amdgcn_mfma_f32_16x16x32_f16(A1, Bw1[1][nt], z, 0, 0, 0);
        acc[nt] = z;
    }
    unsigned short* hs = &Hs[w][0];
#pragma unroll
    for (int nt = 0; nt < 4; ++nt)
#pragma unroll
        for (int r = 0; r < 4; ++r) {
            float hv = fmaxf(acc[nt][r] + b1n[nt], 0.0f);
            hs[(q * 4 + r) * 72 + nt * 16 + m] = f2h_(hv);
        }
    const unsigned short* hrow = hs + m * 72 + q * 8;
    hfrag H0 = *(const hfrag*)(hrow);
    hfrag H1 = *(const hfrag*)(hrow + 32);
    ffrag t2 = {0.f, 0.f, 0.f, 0.f};
    t2 = __builtin_amdgcn_mfma_f32_16x16x32_f16(H0, Bw2[0], t2, 0, 0, 0);
    t2 = __builtin_amdgcn_mfma_f32_16x16x32_f16(H1, Bw2[1], t2, 0, 0, 0);
#pragma unroll
    for (int r = 0; r < 4; ++r)
        t2b[(size_t)(n0 + q * 4 + r) * 16 + m] = f2h_(t2[r]);
}

// ---- layer 2: gather T2 (fp16) + b2 + log_softmax -> out ----
__global__ __launch_bounds__(256) void k_l2(const unsigned short* __restrict__ t2b,
                                            const int* __restrict__ flags,
                                            const float* __restrict__ dis,
                                            const int* __restrict__ row_start,
                                            const int2* __restrict__ pke,
                                            const float* __restrict__ Wbuf,
                                            void* __restrict__ out, int N) {
    int isF32 = flags[0];
    int tid = threadIdx.x, lane = tid & 63;
    int g = lane >> 4, i = lane & 15;
    int n = blockIdx.x * 4 + (tid >> 6);
    if (n >= N) return;
    float dd = dis[n];
    int beg = row_start[n], end = row_start[n + 1];
    int cnt = end - beg;
    float a0 = 0.f, a1 = 0.f;
    if (g == 0) a0 = dd * dd * h2f_(t2b[(size_t)n * 16 + i]);
    int nIt = (cnt + 3) >> 2;
    int p = beg + g;
    int2 e0 = fetchE(pke, p, end);
    int2 e1 = fetchE(pke, p + 4, end);
    int t = 0;
    for (; t + 2 <= nIt; t += 2) {
        float r0 = h2f_(t2b[(size_t)e0.x * 16 + i]);
        float r1 = h2f_(t2b[(size_t)e1.x * 16 + i]);
        float n0v = dd * __int_as_float(e0.y);
        float n1v = dd * __int_as_float(e1.y);
        e0 = fetchE(pke, p + 8, end);
        e1 = fetchE(pke, p + 12, end);
        p += 8;
        a0 += n0v * r0;
        a1 += n1v * r1;
    }
    if (t < nIt) {
        float r0 = h2f_(t2b[(size_t)e0.x * 16 + i]);
        a0 += dd * __int_as_float(e0.y) * r0;
    }
    a0 += a1;
    a0 += __shfl_xor(a0, 16);
    a0 += __shfl_xor(a0, 32);
    float v = a0 + Wbuf[5184 + i];
    float mx = v;
#pragma unroll
    for (int off = 8; off; off >>= 1) mx = fmaxf(mx, __shfl_xor(mx, off, 16));
    float ex = __expf(v - mx);
    float ss = ex;
#pragma unroll
    for (int off = 8; off; off >>= 1) ss += __shfl_xor(ss, off, 16);
    float r = v - mx - logf(ss);
    if (g == 0) {
        size_t oi = (size_t)n * 16 + i;
        if (isF32) ((float*)out)[oi] = r;
        else       ((unsigned short*)out)[oi] = f2b_(r);
    }
}

extern "C" void kernel_launch(void* const* d_in, const int* in_sizes, int n_in,
                              void* d_out, int out_size, void* d_ws, size_t ws_size,
                              hipStream_t stream) {
    const void* x  = d_in[0];
    const int*  ei = (const int*)d_in[1];
    const void* W1 = d_in[2];
    const void* b1 = d_in[3];
    const void* W2 = d_in[4];
    const void* b2 = d_in[5];

    const int N = in_sizes[0] / 64;     // 100000
    const int E = in_sizes[1] / 2;      // 1200000
    const int nbk = (N + LBS - 1) >> BSH;  // 391 coarse buckets

    // 64B-aligned workspace carving (~46 MB)
    char* p = (char*)d_ws;
#define CARVE(ty, name, bytes) ty name = (ty)p; p += (((size_t)(bytes)) + 63) & ~(size_t)63;
    CARVE(int*,   flags,     16)
    CARVE(float*, Wbuf,      5200 * 4)
    CARVE(float*, dis,       (size_t)N * 4)
    CARVE(int*,   row_start, (size_t)(N + 4) * 4)
    CARVE(int*,   dcnt_g,    (size_t)nbk * 2 * 4)      // dcnt | scnt contiguous (one memset)
    int* scnt_g = dcnt_g + nbk;
    CARVE(int*,   dbase_g,   (size_t)(nbk + 4) * 4)
    CARVE(int*,   sbase_g,   (size_t)(nbk + 4) * 4)
    CARVE(int*,   dcur_g,    (size_t)nbk * 4)
    CARVE(int*,   scur_g,    (size_t)nbk * 4)
    CARVE(int*,   pdst,      (size_t)E * 4)
    CARVE(unsigned char*, psrc, (size_t)E)
    CARVE(int2*,  pke,       (size_t)E * 8)
    CARVE(unsigned short*, xh,   (size_t)N * 64 * 2)
    CARVE(unsigned short*, aggb, (size_t)N * 64 * 2)
    CARVE(unsigned short*, t2b,  (size_t)N * 16 * 2)
#undef CARVE

    hipMemsetAsync(dcnt_g, 0, (size_t)nbk * 2 * 4, stream);
    k_cc<<<256, 256, 0, stream>>>(x, ei, W1, b1, W2, b2, E, N, nbk,
                                  flags, Wbuf, dcnt_g, scnt_g, xh);
    k_scan2<<<1, 256, 0, stream>>>(dcnt_g, scnt_g, nbk, E, N,
                                   dbase_g, dcur_g, sbase_g, scur_g, row_start);
    k_bfill<<<256, 256, 0, stream>>>(ei, flags, E, nbk, dcur_g, scur_g, pdst, psrc);
    k_deg<<<nbk, 256, 0, stream>>>(psrc, sbase_g, dis, N);
    k_csr<<<nbk, 256, 0, stream>>>(pdst, dbase_g, dis, row_start, pke, N);
    k_agg<<<(N + 3) / 4, 256, 0, stream>>>(xh, dis, row_start, pke, aggb, N);
    k_dense<<<(N + 63) / 64, 256, 0, stream>>>(aggb, Wbuf, t2b, N);
    k_l2<<<(N + 3) / 4, 256, 0, stream>>>(t2b, flags, dis, row_start, pke, Wbuf, d_out, N);
}